// Round 4
// baseline (194.283 us; speedup 1.0000x reference)
//
#include <hip/hip_runtime.h>
#include <hip/hip_fp16.h>
#include <cmath>

#define N_IMG 128
#define MAX_R 36
#define N_CAP 128
#define MAX_W 32
#define DIM   512
#define NEGV  -1e30f

typedef unsigned short u16;
typedef unsigned int   u32;
typedef __attribute__((ext_vector_type(8))) short short8;
typedef __attribute__((ext_vector_type(4))) float f32x4;

#define NI_ELEMS (N_IMG * MAX_R * DIM)   // 2359296
#define NC_ELEMS (N_CAP * MAX_W * DIM)   // 2097152

// chunk geometry (u16 counts)
#define A_CHUNK_U16 16384   // per (cg8,kb): [hi 256x32][lo 256x32]
#define B_CHUNK_U16 9216    // per (g,kb):   [hi 144x32][lo 144x32]
#define STAGE_BYTES 51200   // 32768 (A) + 18432 (B)
#define SS_FLOATS   (256 * 144)            // 147456 B
#define LDS_BYTES   (147456 + 10368)       // sS + sG16 = 157824 <= 160K

__device__ __forceinline__ u16 f2bf(float x) {
    u32 u = __float_as_uint(x);
    u32 r = u + 0x7fffu + ((u >> 16) & 1u);
    return (u16)(r >> 16);
}
__device__ __forceinline__ float bf2f(u16 h) {
    return __uint_as_float(((u32)h) << 16);
}
__device__ __forceinline__ void gload_lds16(const void* g, void* l) {
    __builtin_amdgcn_global_load_lds(
        (const __attribute__((address_space(1))) void*)g,
        (__attribute__((address_space(3))) void*)l, 16, 0, 0);
}

// ---------------------------------------------------------------------------
// Kernel 0: fp32 -> (hi,lo) bf16 split, pre-tiled + pre-swizzled.
// caps: chunks per (cg8 = c>>3, kb): row = (c&7)*32 + w  (256 rows x 32 k)
// imgs: chunks per (g = imgRow/144, kb): rowT = imgRow % 144 (packed, no pad)
// ---------------------------------------------------------------------------
__global__ __launch_bounds__(256) void convert_kernel(const float* __restrict__ imgs,
                                                      const float* __restrict__ caps,
                                                      u16* __restrict__ imgsT,
                                                      u16* __restrict__ capsT) {
    const size_t ni4 = NI_ELEMS / 4;
    const size_t total4 = (NI_ELEMS + NC_ELEMS) / 4;
    const size_t stride = (size_t)gridDim.x * blockDim.x;
    for (size_t p = (size_t)blockIdx.x * blockDim.x + threadIdx.x; p < total4; p += stride) {
        const bool isImg = p < ni4;
        const float4 v = isImg ? ((const float4*)imgs)[p] : ((const float4*)caps)[p - ni4];
        u16 h0 = f2bf(v.x), h1 = f2bf(v.y), h2 = f2bf(v.z), h3 = f2bf(v.w);
        u16 l0 = f2bf(v.x - bf2f(h0)), l1 = f2bf(v.y - bf2f(h1));
        u16 l2 = f2bf(v.z - bf2f(h2)), l3 = f2bf(v.w - bf2f(h3));
        uint2 hv, lv;
        hv.x = (u32)h0 | ((u32)h1 << 16);  hv.y = (u32)h2 | ((u32)h3 << 16);
        lv.x = (u32)l0 | ((u32)l1 << 16);  lv.y = (u32)l2 | ((u32)l3 << 16);
        if (isImg) {
            const int e = (int)(p * 4);
            const int imgRow = e >> 9, k = e & 511;
            const int g = imgRow / 144;
            const int rowT = imgRow - g * 144;
            const int kb = k >> 5;
            const int blk = ((k >> 3) & 3) ^ ((rowT >> 1) & 3);
            const size_t off = ((size_t)g * 16 + kb) * B_CHUNK_U16 + rowT * 32 + blk * 8 + (k & 7);
            *(uint2*)(imgsT + off) = hv;
            *(uint2*)(imgsT + off + 4608) = lv;
        } else {
            const int e = (int)((p - ni4) * 4);
            const int R = e >> 9, k = e & 511;
            const int cg8 = R >> 8, row = R & 255;
            const int kb = k >> 5;
            const int blk = ((k >> 3) & 3) ^ ((row >> 1) & 3);
            const size_t off = ((size_t)cg8 * 16 + kb) * A_CHUNK_U16 + row * 32 + blk * 8 + (k & 7);
            *(uint2*)(capsT + off) = hv;
            *(uint2*)(capsT + off + 8192) = lv;
        }
    }
}

// ---------------------------------------------------------------------------
// Kernel A: per-image Gram matrices, stored fp16: G16[i][a*36+b]
// ---------------------------------------------------------------------------
__global__ __launch_bounds__(256) void gram_kernel(const float* __restrict__ imgs,
                                                   __half* __restrict__ G16) {
    const int i = blockIdx.x;
    const int t = threadIdx.x;
    __shared__ float sImg[MAX_R][132];
    const float* base = imgs + (size_t)i * MAX_R * DIM;

    const int ap = t / 12;
    const int bt = t % 12;
    const bool active = ap < 18;
    float acc[2][3] = {};

    for (int ch = 0; ch < 4; ++ch) {
        for (int idx = t; idx < MAX_R * 32; idx += 256) {
            const int row = idx >> 5, col = idx & 31;
            *(float4*)&sImg[row][col * 4] =
                *(const float4*)(base + row * DIM + ch * 128 + col * 4);
        }
        __syncthreads();
        if (active) {
            #pragma unroll
            for (int k4 = 0; k4 < 32; ++k4) {
                float4 a0 = *(float4*)&sImg[ap * 2 + 0][k4 * 4];
                float4 a1 = *(float4*)&sImg[ap * 2 + 1][k4 * 4];
                float4 b0 = *(float4*)&sImg[bt * 3 + 0][k4 * 4];
                float4 b1 = *(float4*)&sImg[bt * 3 + 1][k4 * 4];
                float4 b2 = *(float4*)&sImg[bt * 3 + 2][k4 * 4];
                acc[0][0] += a0.x*b0.x + a0.y*b0.y + a0.z*b0.z + a0.w*b0.w;
                acc[0][1] += a0.x*b1.x + a0.y*b1.y + a0.z*b1.z + a0.w*b1.w;
                acc[0][2] += a0.x*b2.x + a0.y*b2.y + a0.z*b2.z + a0.w*b2.w;
                acc[1][0] += a1.x*b0.x + a1.y*b0.y + a1.z*b0.z + a1.w*b0.w;
                acc[1][1] += a1.x*b1.x + a1.y*b1.y + a1.z*b1.z + a1.w*b1.w;
                acc[1][2] += a1.x*b2.x + a1.y*b2.y + a1.z*b2.z + a1.w*b2.w;
            }
        }
        __syncthreads();
    }
    if (active) {
        __half* g = G16 + (size_t)i * (MAX_R * MAX_R);
        #pragma unroll
        for (int x = 0; x < 2; ++x)
            #pragma unroll
            for (int y = 0; y < 3; ++y)
                g[(ap * 2 + x) * MAX_R + (bt * 3 + y)] = __float2half(acc[x][y]);
    }
}

// ---------------------------------------------------------------------------
// Kernel B: block = 8 caps (256 rows) x 4 images (144 packed cols).
// 6 waves (2m x 3n), wave tile 128x48, 16x16x32 bf16 MFMA, 3-pass hi/lo.
// Double-buffered global_load_lds staging, stage(next) before compute(cur).
// Dynamic LDS: [0,102400) staging | sS 256x144 f32 overlay | sG16 at 147456.
// ---------------------------------------------------------------------------
__global__ void vsc_mfma_kernel(const u16* __restrict__ imgsT,
                                const u16* __restrict__ capsT,
                                const int* __restrict__ img_lens,
                                const int* __restrict__ cap_lens,
                                const __half* __restrict__ G16,
                                float* __restrict__ out) {
    extern __shared__ __align__(16) char smem[];
    const int bid = blockIdx.x;
    const int g   = bid >> 4;     // image tile 0..31 (4 imgs each)
    const int cg8 = bid & 15;     // cap group 0..15 (8 caps each)
    const int t = threadIdx.x;
    const int wid = t >> 6;       // 0..5
    const int lane = t & 63;
    const int l15 = lane & 15;
    const int kblk = lane >> 4;
    const int wm = (wid < 3) ? 0 : 1;
    const int wn = wid - wm * 3;

    float* sS = (float*)smem;
    __half* sG = (__half*)(smem + 147456);

    // prologue: Gram (4 images, fp16) into LDS
    {
        const uint4* src = (const uint4*)(G16 + (size_t)g * 4 * 1296);
        for (int idx = t; idx < 648; idx += 384)
            ((uint4*)sG)[idx] = src[idx];
    }

    const char* gA = (const char*)(capsT + (size_t)cg8 * 16 * A_CHUNK_U16);
    const char* gB = (const char*)(imgsT + (size_t)g  * 16 * B_CHUNK_U16);

    auto stage = [&](int kb, char* buf) {
        if (wid < 4) {          // A: 32768 B, 4 waves x 8 KB
            const char* src = gA + (size_t)kb * 32768 + wid * 8192 + lane * 16;
            char* dst = buf + wid * 8192;
            #pragma unroll
            for (int j = 0; j < 8; ++j)
                gload_lds16(src + j * 1024, dst + j * 1024);
        } else {                // B: 18432 B, 2 waves x 9 KB
            const int wb = wid - 4;
            const char* src = gB + (size_t)kb * 18432 + wb * 9216 + lane * 16;
            char* dst = buf + 32768 + wb * 9216;
            #pragma unroll
            for (int j = 0; j < 9; ++j)
                gload_lds16(src + j * 1024, dst + j * 1024);
        }
    };

    f32x4 acc[8][3];
    #pragma unroll
    for (int mt = 0; mt < 8; ++mt)
        #pragma unroll
        for (int nt = 0; nt < 3; ++nt)
            acc[mt][nt] = (f32x4){0.f, 0.f, 0.f, 0.f};

    stage(0, smem);
    __syncthreads();

    for (int kb = 0; kb < 16; ++kb) {
        char* cur = smem + (size_t)(kb & 1) * STAGE_BYTES;
        if (kb < 15) stage(kb + 1, smem + (size_t)((kb + 1) & 1) * STAGE_BYTES);

        short8 bh[3], bl[3], ah[8], al[8];
        #pragma unroll
        for (int nt = 0; nt < 3; ++nt) {
            const int r = wn * 48 + nt * 16 + l15;
            const int blk = kblk ^ ((r >> 1) & 3);
            bh[nt] = *(const short8*)(cur + 32768 + r * 64 + blk * 16);
            bl[nt] = *(const short8*)(cur + 32768 + 9216 + r * 64 + blk * 16);
        }
        #pragma unroll
        for (int mt = 0; mt < 8; ++mt) {
            const int row = wm * 128 + mt * 16 + l15;
            const int blk = kblk ^ ((row >> 1) & 3);
            ah[mt] = *(const short8*)(cur + row * 64 + blk * 16);
            al[mt] = *(const short8*)(cur + 16384 + row * 64 + blk * 16);
        }
        #pragma unroll
        for (int mt = 0; mt < 8; ++mt)
            #pragma unroll
            for (int nt = 0; nt < 3; ++nt) {
                acc[mt][nt] = __builtin_amdgcn_mfma_f32_16x16x32_bf16(ah[mt], bh[nt], acc[mt][nt], 0, 0, 0);
                acc[mt][nt] = __builtin_amdgcn_mfma_f32_16x16x32_bf16(ah[mt], bl[nt], acc[mt][nt], 0, 0, 0);
                acc[mt][nt] = __builtin_amdgcn_mfma_f32_16x16x32_bf16(al[mt], bh[nt], acc[mt][nt], 0, 0, 0);
            }
        __syncthreads();
    }

    // ---- sims -> LDS overlay (already / TEMPERATURE); col-XOR bank swizzle
    #pragma unroll
    for (int mt = 0; mt < 8; ++mt)
        #pragma unroll
        for (int nt = 0; nt < 3; ++nt) {
            const int col = wn * 48 + nt * 16 + l15;
            #pragma unroll
            for (int reg = 0; reg < 4; ++reg) {
                const int row = wm * 128 + mt * 16 + (lane >> 4) * 4 + reg;
                sS[row * 144 + (col ^ ((row >> 1) & 15))] = acc[mt][nt][reg] * 10.f;
            }
        }
    __syncthreads();

    // ---- postprocess: 1024 tasks = 256 (cap,w) pairs x 4 images
    for (int task = t; task < 1024; task += 384) {
        const int pair = task & 255;
        const int j = task >> 8;        // image within tile
        const int q = pair >> 5, w = pair & 31;
        const int c = cg8 * 8 + q;
        const int i = g * 4 + j;
        float result = -1.0f;
        if (w < cap_lens[c]) {
            const int ilen = img_lens[i];   // >= 6 by construction
            const float* rowp = sS + pair * 144;
            const int xv = (pair >> 1) & 15;
            const int cb = j * 36;
            float t0 = NEGV, t1 = NEGV, t2 = NEGV, t3 = NEGV, t4 = NEGV;
            for (int r = 0; r < ilen; ++r) {
                const float v = rowp[(cb + r) ^ xv];
                if (v > t4) {
                    if (v > t0)      { t4=t3; t3=t2; t2=t1; t1=t0; t0=v; }
                    else if (v > t1) { t4=t3; t3=t2; t2=t1; t1=v; }
                    else if (v > t2) { t4=t3; t3=t2; t2=v; }
                    else if (v > t3) { t4=t3; t3=v; }
                    else             { t4=v; }
                }
            }
            const float kth = t4, m = t0;
            int   idxs[8];
            float pv[8];
            int cnt = 0;
            float sum = 0.f;
            for (int r = 0; r < ilen; ++r) {
                const float v = rowp[(cb + r) ^ xv];
                if (v >= kth) {
                    const float e = expf(v - m);
                    sum += e;
                    if (cnt < 8) { idxs[cnt] = r; pv[cnt] = e; ++cnt; }
                }
            }
            const float inv = 1.0f / sum;
            const __half* gj = sG + j * 1296;
            float num = 0.f, den2 = 0.f;
            for (int a = 0; a < cnt; ++a) {
                const float pa = pv[a] * inv;
                num += pa * rowp[(cb + idxs[a]) ^ xv];
                for (int b = 0; b < cnt; ++b)
                    den2 += pa * (pv[b] * inv) * __half2float(gj[idxs[a] * 36 + idxs[b]]);
            }
            num *= 0.1f;
            const float den = sqrtf(den2) + (-1e-8f);
            result = num / den;
        }
        out[((size_t)i * N_CAP + c) * MAX_W + w] = result;
    }
}

extern "C" void kernel_launch(void* const* d_in, const int* in_sizes, int n_in,
                              void* d_out, int out_size, void* d_ws, size_t ws_size,
                              hipStream_t stream) {
    const float* imgs     = (const float*)d_in[0];
    const float* caps     = (const float*)d_in[1];
    const int*   img_lens = (const int*)d_in[2];
    const int*   cap_lens = (const int*)d_in[3];
    float* out = (float*)d_out;

    // d_ws layout
    __half* G16 = (__half*)d_ws;                               // 128*1296*2 = 331776 B
    u16* imgsT = (u16*)((char*)d_ws + 331776);                 // 32*16*9216 u16 = 9437184 B
    u16* capsT = imgsT + (size_t)32 * 16 * B_CHUNK_U16;        // 16*16*16384 u16 = 8388608 B

    hipFuncSetAttribute((const void*)vsc_mfma_kernel,
                        hipFuncAttributeMaxDynamicSharedMemorySize, LDS_BYTES);

    convert_kernel<<<2048, 256, 0, stream>>>(imgs, caps, imgsT, capsT);
    gram_kernel<<<N_IMG, 256, 0, stream>>>(imgs, G16);
    vsc_mfma_kernel<<<512, 384, LDS_BYTES, stream>>>(imgsT, capsT, img_lens, cap_lens, G16, out);
}

// Round 5
// 157.412 us; speedup vs baseline: 1.2342x; 1.2342x over previous
//
#include <hip/hip_runtime.h>
#include <hip/hip_fp16.h>
#include <cmath>

#define N_IMG 128
#define MAX_R 36
#define N_CAP 128
#define MAX_W 32
#define DIM   512
#define NEGV  -1e30f

typedef unsigned short u16;
typedef unsigned int   u32;
typedef __attribute__((ext_vector_type(8))) short short8;
typedef __attribute__((ext_vector_type(4))) float f32x4;

#define NI_ELEMS (N_IMG * MAX_R * DIM)   // 2359296
#define NC_ELEMS (N_CAP * MAX_W * DIM)   // 2097152

// chunk geometry (u16 counts)
#define A_CHUNK_U16 16384   // per (cg8,kb): [hi 256x32][lo 256x32]
#define B_CHUNK_U16 9216    // per (g,kb):   [hi 144x32][lo 144x32]
#define STAGE_BYTES 51200   // 32768 (A) + 18432 (B)
#define SS_FLOATS   (256 * 144)            // 147456 B
#define LDS_BYTES   (147456 + 10368)       // sS + sG16 = 157824 <= 160K

__device__ __forceinline__ u16 f2bf(float x) {
    u32 u = __float_as_uint(x);
    u32 r = u + 0x7fffu + ((u >> 16) & 1u);
    return (u16)(r >> 16);
}
__device__ __forceinline__ float bf2f(u16 h) {
    return __uint_as_float(((u32)h) << 16);
}
__device__ __forceinline__ void gload_lds16(const void* g, void* l) {
    __builtin_amdgcn_global_load_lds(
        (const __attribute__((address_space(1))) void*)g,
        (__attribute__((address_space(3))) void*)l, 16, 0, 0);
}

// ---------------------------------------------------------------------------
// Kernel 0: fp32 -> (hi,lo) bf16 split, pre-tiled + pre-swizzled.
// ---------------------------------------------------------------------------
__global__ __launch_bounds__(256) void convert_kernel(const float* __restrict__ imgs,
                                                      const float* __restrict__ caps,
                                                      u16* __restrict__ imgsT,
                                                      u16* __restrict__ capsT) {
    const size_t ni4 = NI_ELEMS / 4;
    const size_t total4 = (NI_ELEMS + NC_ELEMS) / 4;
    const size_t stride = (size_t)gridDim.x * blockDim.x;
    for (size_t p = (size_t)blockIdx.x * blockDim.x + threadIdx.x; p < total4; p += stride) {
        const bool isImg = p < ni4;
        const float4 v = isImg ? ((const float4*)imgs)[p] : ((const float4*)caps)[p - ni4];
        u16 h0 = f2bf(v.x), h1 = f2bf(v.y), h2 = f2bf(v.z), h3 = f2bf(v.w);
        u16 l0 = f2bf(v.x - bf2f(h0)), l1 = f2bf(v.y - bf2f(h1));
        u16 l2 = f2bf(v.z - bf2f(h2)), l3 = f2bf(v.w - bf2f(h3));
        uint2 hv, lv;
        hv.x = (u32)h0 | ((u32)h1 << 16);  hv.y = (u32)h2 | ((u32)h3 << 16);
        lv.x = (u32)l0 | ((u32)l1 << 16);  lv.y = (u32)l2 | ((u32)l3 << 16);
        if (isImg) {
            const int e = (int)(p * 4);
            const int imgRow = e >> 9, k = e & 511;
            const int g = imgRow / 144;
            const int rowT = imgRow - g * 144;
            const int kb = k >> 5;
            const int blk = ((k >> 3) & 3) ^ ((rowT >> 1) & 3);
            const size_t off = ((size_t)g * 16 + kb) * B_CHUNK_U16 + rowT * 32 + blk * 8 + (k & 7);
            *(uint2*)(imgsT + off) = hv;
            *(uint2*)(imgsT + off + 4608) = lv;
        } else {
            const int e = (int)((p - ni4) * 4);
            const int R = e >> 9, k = e & 511;
            const int cg8 = R >> 8, row = R & 255;
            const int kb = k >> 5;
            const int blk = ((k >> 3) & 3) ^ ((row >> 1) & 3);
            const size_t off = ((size_t)cg8 * 16 + kb) * A_CHUNK_U16 + row * 32 + blk * 8 + (k & 7);
            *(uint2*)(capsT + off) = hv;
            *(uint2*)(capsT + off + 8192) = lv;
        }
    }
}

// ---------------------------------------------------------------------------
// Kernel A: per-image Gram matrices, stored fp16: G16[i][a*36+b]
// ---------------------------------------------------------------------------
__global__ __launch_bounds__(256) void gram_kernel(const float* __restrict__ imgs,
                                                   __half* __restrict__ G16) {
    const int i = blockIdx.x;
    const int t = threadIdx.x;
    __shared__ float sImg[MAX_R][132];
    const float* base = imgs + (size_t)i * MAX_R * DIM;

    const int ap = t / 12;
    const int bt = t % 12;
    const bool active = ap < 18;
    float acc[2][3] = {};

    for (int ch = 0; ch < 4; ++ch) {
        for (int idx = t; idx < MAX_R * 32; idx += 256) {
            const int row = idx >> 5, col = idx & 31;
            *(float4*)&sImg[row][col * 4] =
                *(const float4*)(base + row * DIM + ch * 128 + col * 4);
        }
        __syncthreads();
        if (active) {
            #pragma unroll
            for (int k4 = 0; k4 < 32; ++k4) {
                float4 a0 = *(float4*)&sImg[ap * 2 + 0][k4 * 4];
                float4 a1 = *(float4*)&sImg[ap * 2 + 1][k4 * 4];
                float4 b0 = *(float4*)&sImg[bt * 3 + 0][k4 * 4];
                float4 b1 = *(float4*)&sImg[bt * 3 + 1][k4 * 4];
                float4 b2 = *(float4*)&sImg[bt * 3 + 2][k4 * 4];
                acc[0][0] += a0.x*b0.x + a0.y*b0.y + a0.z*b0.z + a0.w*b0.w;
                acc[0][1] += a0.x*b1.x + a0.y*b1.y + a0.z*b1.z + a0.w*b1.w;
                acc[0][2] += a0.x*b2.x + a0.y*b2.y + a0.z*b2.z + a0.w*b2.w;
                acc[1][0] += a1.x*b0.x + a1.y*b0.y + a1.z*b0.z + a1.w*b0.w;
                acc[1][1] += a1.x*b1.x + a1.y*b1.y + a1.z*b1.z + a1.w*b1.w;
                acc[1][2] += a1.x*b2.x + a1.y*b2.y + a1.z*b2.z + a1.w*b2.w;
            }
        }
        __syncthreads();
    }
    if (active) {
        __half* g = G16 + (size_t)i * (MAX_R * MAX_R);
        #pragma unroll
        for (int x = 0; x < 2; ++x)
            #pragma unroll
            for (int y = 0; y < 3; ++y)
                g[(ap * 2 + x) * MAX_R + (bt * 3 + y)] = __float2half(acc[x][y]);
    }
}

// ---------------------------------------------------------------------------
// Kernel B: block = 8 caps (256 rows) x 4 images (144 packed cols).
// 6 waves (2m x 3n), wave tile 128x48, 16x16x32 bf16 MFMA, 3-pass hi/lo.
// __launch_bounds__(384,1): R4 lesson — without it hipcc assumes 1024-thr
// blocks and caps VGPR at 64 -> acc[8][3] spills to scratch (19MB WRITE_SIZE).
// ---------------------------------------------------------------------------
__global__ __launch_bounds__(384, 1) void vsc_mfma_kernel(const u16* __restrict__ imgsT,
                                const u16* __restrict__ capsT,
                                const int* __restrict__ img_lens,
                                const int* __restrict__ cap_lens,
                                const __half* __restrict__ G16,
                                float* __restrict__ out) {
    extern __shared__ __align__(16) char smem[];
    const int bid = blockIdx.x;
    const int g   = bid >> 4;     // image tile 0..31 (4 imgs each)
    const int cg8 = bid & 15;     // cap group 0..15 (8 caps each)
    const int t = threadIdx.x;
    const int wid = t >> 6;       // 0..5
    const int lane = t & 63;
    const int l15 = lane & 15;
    const int kblk = lane >> 4;
    const int wm = (wid < 3) ? 0 : 1;
    const int wn = wid - wm * 3;

    float* sS = (float*)smem;
    __half* sG = (__half*)(smem + 147456);

    // prologue: Gram (4 images, fp16) into LDS
    {
        const uint4* src = (const uint4*)(G16 + (size_t)g * 4 * 1296);
        for (int idx = t; idx < 648; idx += 384)
            ((uint4*)sG)[idx] = src[idx];
    }

    const char* gA = (const char*)(capsT + (size_t)cg8 * 16 * A_CHUNK_U16);
    const char* gB = (const char*)(imgsT + (size_t)g  * 16 * B_CHUNK_U16);

    auto stage = [&](int kb, char* buf) {
        if (wid < 4) {          // A: 32768 B, 4 waves x 8 KB
            const char* src = gA + (size_t)kb * 32768 + wid * 8192 + lane * 16;
            char* dst = buf + wid * 8192;
            #pragma unroll
            for (int j = 0; j < 8; ++j)
                gload_lds16(src + j * 1024, dst + j * 1024);
        } else {                // B: 18432 B, 2 waves x 9 KB
            const int wb = wid - 4;
            const char* src = gB + (size_t)kb * 18432 + wb * 9216 + lane * 16;
            char* dst = buf + 32768 + wb * 9216;
            #pragma unroll
            for (int j = 0; j < 9; ++j)
                gload_lds16(src + j * 1024, dst + j * 1024);
        }
    };

    f32x4 acc[8][3];
    #pragma unroll
    for (int mt = 0; mt < 8; ++mt)
        #pragma unroll
        for (int nt = 0; nt < 3; ++nt)
            acc[mt][nt] = (f32x4){0.f, 0.f, 0.f, 0.f};

    stage(0, smem);
    __syncthreads();

    for (int kb = 0; kb < 16; ++kb) {
        char* cur = smem + (size_t)(kb & 1) * STAGE_BYTES;
        if (kb < 15) stage(kb + 1, smem + (size_t)((kb + 1) & 1) * STAGE_BYTES);

        short8 bh[3], bl[3], ah[8], al[8];
        #pragma unroll
        for (int nt = 0; nt < 3; ++nt) {
            const int r = wn * 48 + nt * 16 + l15;
            const int blk = kblk ^ ((r >> 1) & 3);
            bh[nt] = *(const short8*)(cur + 32768 + r * 64 + blk * 16);
            bl[nt] = *(const short8*)(cur + 32768 + 9216 + r * 64 + blk * 16);
        }
        #pragma unroll
        for (int mt = 0; mt < 8; ++mt) {
            const int row = wm * 128 + mt * 16 + l15;
            const int blk = kblk ^ ((row >> 1) & 3);
            ah[mt] = *(const short8*)(cur + row * 64 + blk * 16);
            al[mt] = *(const short8*)(cur + 16384 + row * 64 + blk * 16);
        }
        #pragma unroll
        for (int mt = 0; mt < 8; ++mt)
            #pragma unroll
            for (int nt = 0; nt < 3; ++nt) {
                acc[mt][nt] = __builtin_amdgcn_mfma_f32_16x16x32_bf16(ah[mt], bh[nt], acc[mt][nt], 0, 0, 0);
                acc[mt][nt] = __builtin_amdgcn_mfma_f32_16x16x32_bf16(ah[mt], bl[nt], acc[mt][nt], 0, 0, 0);
                acc[mt][nt] = __builtin_amdgcn_mfma_f32_16x16x32_bf16(al[mt], bh[nt], acc[mt][nt], 0, 0, 0);
            }
        __syncthreads();
    }

    // ---- sims -> LDS overlay (already / TEMPERATURE); col-XOR bank swizzle
    #pragma unroll
    for (int mt = 0; mt < 8; ++mt)
        #pragma unroll
        for (int nt = 0; nt < 3; ++nt) {
            const int col = wn * 48 + nt * 16 + l15;
            #pragma unroll
            for (int reg = 0; reg < 4; ++reg) {
                const int row = wm * 128 + mt * 16 + (lane >> 4) * 4 + reg;
                sS[row * 144 + (col ^ ((row >> 1) & 15))] = acc[mt][nt][reg] * 10.f;
            }
        }
    __syncthreads();

    // ---- postprocess: 1024 tasks = 256 (cap,w) pairs x 4 images
    for (int task = t; task < 1024; task += 384) {
        const int pair = task & 255;
        const int j = task >> 8;        // image within tile
        const int q = pair >> 5, w = pair & 31;
        const int c = cg8 * 8 + q;
        const int i = g * 4 + j;
        float result = -1.0f;
        if (w < cap_lens[c]) {
            const int ilen = img_lens[i];   // >= 6 by construction
            const float* rowp = sS + pair * 144;
            const int xv = (pair >> 1) & 15;
            const int cb = j * 36;
            float t0 = NEGV, t1 = NEGV, t2 = NEGV, t3 = NEGV, t4 = NEGV;
            for (int r = 0; r < ilen; ++r) {
                const float v = rowp[(cb + r) ^ xv];
                if (v > t4) {
                    if (v > t0)      { t4=t3; t3=t2; t2=t1; t1=t0; t0=v; }
                    else if (v > t1) { t4=t3; t3=t2; t2=t1; t1=v; }
                    else if (v > t2) { t4=t3; t3=t2; t2=v; }
                    else if (v > t3) { t4=t3; t3=v; }
                    else             { t4=v; }
                }
            }
            const float kth = t4, m = t0;
            int   idxs[8];
            float pv[8];
            int cnt = 0;
            float sum = 0.f;
            for (int r = 0; r < ilen; ++r) {
                const float v = rowp[(cb + r) ^ xv];
                if (v >= kth) {
                    const float e = expf(v - m);
                    sum += e;
                    if (cnt < 8) { idxs[cnt] = r; pv[cnt] = e; ++cnt; }
                }
            }
            const float inv = 1.0f / sum;
            const __half* gj = sG + j * 1296;
            float num = 0.f, den2 = 0.f;
            for (int a = 0; a < cnt; ++a) {
                const float pa = pv[a] * inv;
                num += pa * rowp[(cb + idxs[a]) ^ xv];
                for (int b = 0; b < cnt; ++b)
                    den2 += pa * (pv[b] * inv) * __half2float(gj[idxs[a] * 36 + idxs[b]]);
            }
            num *= 0.1f;
            const float den = sqrtf(den2) + (-1e-8f);
            result = num / den;
        }
        out[((size_t)i * N_CAP + c) * MAX_W + w] = result;
    }
}

extern "C" void kernel_launch(void* const* d_in, const int* in_sizes, int n_in,
                              void* d_out, int out_size, void* d_ws, size_t ws_size,
                              hipStream_t stream) {
    const float* imgs     = (const float*)d_in[0];
    const float* caps     = (const float*)d_in[1];
    const int*   img_lens = (const int*)d_in[2];
    const int*   cap_lens = (const int*)d_in[3];
    float* out = (float*)d_out;

    // d_ws layout
    __half* G16 = (__half*)d_ws;                               // 128*1296*2 = 331776 B
    u16* imgsT = (u16*)((char*)d_ws + 331776);                 // 32*16*9216 u16 = 9437184 B
    u16* capsT = imgsT + (size_t)32 * 16 * B_CHUNK_U16;        // 16*16*16384 u16 = 8388608 B

    hipFuncSetAttribute((const void*)vsc_mfma_kernel,
                        hipFuncAttributeMaxDynamicSharedMemorySize, LDS_BYTES);

    convert_kernel<<<2048, 256, 0, stream>>>(imgs, caps, imgsT, capsT);
    gram_kernel<<<N_IMG, 256, 0, stream>>>(imgs, G16);
    vsc_mfma_kernel<<<512, 384, LDS_BYTES, stream>>>(imgsT, capsT, img_lens, cap_lens, G16, out);
}